// Round 1
// baseline (14014.514 us; speedup 1.0000x reference)
//
#include <hip/hip_runtime.h>
#include <math.h>

#define N_TOK 1024
#define DV    400
#define G4    1600
#define DWD   300
#define DPD   100
#define HID   512
#define FD    128
#define GWG   50      // workgroups per LSTM direction
#define EPW   8       // hidden elements per WG (DV / GWG)

__device__ __forceinline__ float sigmoidf_(float x){ return 1.0f/(1.0f+__expf(-x)); }

// ---------------- embedding gather: x[t] = [word_emb[wid], pos_emb[pid]] ----------------
__global__ void k_gather(const int* __restrict__ wid, const int* __restrict__ pid,
                         const float* __restrict__ wemb, const float* __restrict__ pemb,
                         float* __restrict__ x)
{
    int t = blockIdx.x;
    int w = wid[t], p = pid[t];
    for (int k = threadIdx.x; k < DV; k += blockDim.x){
        float v = (k < DWD) ? wemb[(long)w*DWD + k] : pemb[p*DPD + (k - DWD)];
        x[t*DV + k] = v;
    }
}

// ---------------- tiny transpose (U_1 -> U_1^T) ----------------
__global__ void k_transpose(const float* __restrict__ U, float* __restrict__ Ut, int n)
{
    int j = blockIdx.y*16 + threadIdx.y;
    int k = blockIdx.x*16 + threadIdx.x;
    if (j < n && k < n) Ut[j*n + k] = U[k*n + j];
}

// ---------------- fp32 NT GEMM: C[M][Nn] = A[M][K] * B[Nn][K]^T (+biases, relu) -------
// revA: read A rows reversed (for backward LSTM input projection)
__global__ __launch_bounds__(256) void k_gemm_nt(
    const float* __restrict__ A, const float* __restrict__ B,
    const float* __restrict__ bias1, const float* __restrict__ bias2,
    const float* __restrict__ rowbias, float* __restrict__ C,
    int M, int Nn, int K, int revA, int relu)
{
    const int BM = 64, BN = 64, BK = 16;
    __shared__ float As[BK][BM];
    __shared__ float Bs[BK][BN];
    int tid = threadIdx.x;
    int tx = tid & 15, ty = tid >> 4;
    int m0 = blockIdx.y*BM, n0 = blockIdx.x*BN;
    int lrow = tid >> 2;          // 0..63
    int lk   = (tid & 3) * 4;     // 0,4,8,12
    float acc[4][4] = {{0.f}};

    for (int k0 = 0; k0 < K; k0 += BK){
        int am = m0 + lrow; if (revA) am = M - 1 - am;
        const float4 av = *(const float4*)&A[(long)am*K + k0 + lk];
        const float4 bv = *(const float4*)&B[(long)(n0 + lrow)*K + k0 + lk];
        As[lk+0][lrow] = av.x; As[lk+1][lrow] = av.y; As[lk+2][lrow] = av.z; As[lk+3][lrow] = av.w;
        Bs[lk+0][lrow] = bv.x; Bs[lk+1][lrow] = bv.y; Bs[lk+2][lrow] = bv.z; Bs[lk+3][lrow] = bv.w;
        __syncthreads();
        #pragma unroll
        for (int kk = 0; kk < BK; ++kk){
            const float4 a = *(const float4*)&As[kk][ty*4];
            const float4 b = *(const float4*)&Bs[kk][tx*4];
            const float ar[4] = {a.x, a.y, a.z, a.w};
            const float br[4] = {b.x, b.y, b.z, b.w};
            #pragma unroll
            for (int i = 0; i < 4; ++i)
                #pragma unroll
                for (int j = 0; j < 4; ++j)
                    acc[i][j] += ar[i]*br[j];
        }
        __syncthreads();
    }

    #pragma unroll
    for (int i = 0; i < 4; ++i){
        int m = m0 + ty*4 + i;
        float rb = rowbias ? rowbias[m] : 0.0f;
        #pragma unroll
        for (int j = 0; j < 4; ++j){
            int n = n0 + tx*4 + j;
            float v = acc[i][j] + rb;
            if (bias1) v += bias1[n];
            if (bias2) v += bias2[n];
            if (relu)  v = fmaxf(v, 0.0f);
            C[(long)m*Nn + n] = v;
        }
    }
}

// ---------------- persistent BiLSTM with agent-scope step barrier ----------------
// grid = 2*GWG blocks of 256. dir = blockIdx.x/GWG. WG g owns elements j0..j0+7 and
// the 4*8=32 corresponding gate rows of Whh (staged in LDS).
__global__ __launch_bounds__(256) void k_lstm(
    const float* __restrict__ Whh_f, const float* __restrict__ Whh_b,
    const float* __restrict__ Xf, const float* __restrict__ Xb,
    const float* __restrict__ h0, const float* __restrict__ c0,
    float* __restrict__ hf, float* __restrict__ hb,
    int* __restrict__ flags)
{
    __shared__ float W_s[32][DV];   // 51.2 KB
    __shared__ float h_s[DV];

    int tid = threadIdx.x;
    int dir = blockIdx.x / GWG;
    int g   = blockIdx.x % GWG;
    int j0  = g * EPW;
    const float* Whh = dir ? Whh_b : Whh_f;
    const float* XX  = dir ? Xb    : Xf;
    float*       hout= dir ? hb    : hf;
    int*         flag= flags + dir * N_TOK;

    // stage weight slice: local row r = q*8+e  ->  global gate row q*DV + j0 + e
    for (int idx = tid; idx < 32*DV; idx += 256){
        int r = idx / DV, k = idx % DV;
        int grow = (r >> 3) * DV + j0 + (r & 7);
        W_s[r][k] = Whh[(long)grow*DV + k];
    }
    for (int idx = tid; idx < DV; idx += 256) h_s[idx] = h0[dir*DV + idx];

    int w    = tid >> 6;        // wave 0..3
    int lane = tid & 63;
    int q    = lane >> 4;       // gate 0..3 (i,f,g,o)
    int eo   = (lane >> 3) & 1; // element parity within wave
    int l    = lane & 7;        // lane within row octet
    int e    = 2*w + eo;        // element 0..7 owned by this octet's wave
    int r    = q*8 + e;         // local weight row
    int grow = q*DV + j0 + e;   // global gate index
    bool owner = (q == 0) && (l == 0);  // lanes 0 and 8 of each wave
    float c_reg = owner ? c0[dir*DV + j0 + e] : 0.0f;
    __syncthreads();

    bool dead = false;
    for (int t = 0; t < N_TOK; ++t){
        float xv = 0.0f;
        if (l == 0) xv = XX[(long)t*G4 + grow];   // issued early, consumed after dot

        // matvec: row r dot h  (8 lanes/row, float2 each)
        float sum = 0.0f;
        const float2* wrow = (const float2*)&W_s[r][0];
        const float2* hp   = (const float2*)&h_s[0];
        #pragma unroll
        for (int i = 0; i < 25; ++i){
            float2 wv = wrow[l + 8*i];
            float2 hv = hp[l + 8*i];
            sum += wv.x*hv.x + wv.y*hv.y;
        }
        sum += __shfl_xor(sum, 1, 8);
        sum += __shfl_xor(sum, 2, 8);
        sum += __shfl_xor(sum, 4, 8);
        if (l == 0) sum += xv;

        // collect the 4 gate totals for my wave's element e (srcs are l==0 lanes)
        float gi = __shfl(sum, eo*8 + 0,  64);
        float gf = __shfl(sum, eo*8 + 16, 64);
        float gg = __shfl(sum, eo*8 + 32, 64);
        float go = __shfl(sum, eo*8 + 48, 64);

        if (owner){
            float iv = sigmoidf_(gi);
            float fv = sigmoidf_(gf);
            float gv = tanhf(gg);
            float ov = sigmoidf_(go);
            c_reg = fv*c_reg + iv*gv;
            float hv = ov * tanhf(c_reg);
            __hip_atomic_store(&hout[(long)t*DV + j0 + e], hv,
                               __ATOMIC_RELEASE, __HIP_MEMORY_SCOPE_AGENT);
        }
        __syncthreads();   // vmcnt(0) drain: all 8 element stores globally visible
        if (tid == 0)
            __hip_atomic_fetch_add(&flag[t], 1, __ATOMIC_RELAXED, __HIP_MEMORY_SCOPE_AGENT);

        if (!dead){
            int guard = 0;
            while (__hip_atomic_load(&flag[t], __ATOMIC_ACQUIRE, __HIP_MEMORY_SCOPE_AGENT) < GWG){
                __builtin_amdgcn_s_sleep(1);
                if (++guard > (1 << 20)) { dead = true; break; }  // safety: no infinite hang
            }
        }
        // restage full h[t] (agent-scope loads: coherent via IF$)
        for (int idx = tid; idx < DV; idx += 256)
            h_s[idx] = __hip_atomic_load(&hout[(long)t*DV + idx],
                                         __ATOMIC_RELAXED, __HIP_MEMORY_SCOPE_AGENT);
        __syncthreads();
    }
}

// ---------------- sr = sigmoid(concat(hf[t], hb[N-1-t])) ----------------
__global__ void k_sr(const float* __restrict__ hf, const float* __restrict__ hb,
                     float* __restrict__ sr)
{
    int t = blockIdx.x;
    for (int c = threadIdx.x; c < 2*DV; c += blockDim.x){
        float v = (c < DV) ? hf[t*DV + c] : hb[(N_TOK-1-t)*DV + (c - DV)];
        sr[t*2*DV + c] = 1.0f/(1.0f+__expf(-v));
    }
}

// ---------------- bvec[i] = dot(Hh[i], u2) ----------------
__global__ void k_bvec(const float* __restrict__ Hh, const float* __restrict__ u2,
                       float* __restrict__ bvec)
{
    int i = blockIdx.x;
    int lane = threadIdx.x;
    float v = Hh[i*FD + lane]*u2[lane] + Hh[i*FD + 64 + lane]*u2[64 + lane];
    v += __shfl_xor(v, 1, 64);
    v += __shfl_xor(v, 2, 64);
    v += __shfl_xor(v, 4, 64);
    v += __shfl_xor(v, 8, 64);
    v += __shfl_xor(v, 16, 64);
    v += __shfl_xor(v, 32, 64);
    if (lane == 0) bvec[i] = v;
}

extern "C" void kernel_launch(void* const* d_in, const int* in_sizes, int n_in,
                              void* d_out, int out_size, void* d_ws, size_t ws_size,
                              hipStream_t stream)
{
    const int*   word_ids = (const int*)  d_in[0];
    const int*   pos_ids  = (const int*)  d_in[1];
    const float* h0    = (const float*)d_in[2];
    const float* c0    = (const float*)d_in[3];
    const float* wemb  = (const float*)d_in[4];
    const float* pemb  = (const float*)d_in[5];
    const float* Wih_f = (const float*)d_in[6];
    const float* Whh_f = (const float*)d_in[7];
    const float* bih_f = (const float*)d_in[8];
    const float* bhh_f = (const float*)d_in[9];
    const float* Wih_b = (const float*)d_in[10];
    const float* Whh_b = (const float*)d_in[11];
    const float* bih_b = (const float*)d_in[12];
    const float* bhh_b = (const float*)d_in[13];
    const float* Wh1   = (const float*)d_in[14];
    const float* bh1   = (const float*)d_in[15];
    const float* Wh2   = (const float*)d_in[16];
    const float* bh2   = (const float*)d_in[17];
    const float* Wd1   = (const float*)d_in[18];
    const float* bd1   = (const float*)d_in[19];
    const float* Wd2   = (const float*)d_in[20];
    const float* bd2   = (const float*)d_in[21];
    const float* U1    = (const float*)d_in[22];
    const float* u2    = (const float*)d_in[23];
    float* out = (float*)d_out;

    // workspace layout (floats)
    float* ws  = (float*)d_ws;
    float* x    = ws;                 // 1024*400
    float* Xf   = ws + 409600;        // 1024*1600
    float* Xb   = ws + 2048000;       // 1024*1600
    float* hf   = ws + 3686400;       // 1024*400
    float* hb   = ws + 4096000;       // 1024*400
    float* sr   = ws + 4505600;       // 1024*800
    float* T1h  = ws + 5324800;       // 1024*512
    float* T1d  = ws + 5849088;       // 1024*512
    float* Hh   = ws + 6373376;       // 1024*128
    float* Hd   = ws + 6504448;       // 1024*128
    float* G1   = ws + 6635520;       // 1024*128
    float* Ut   = ws + 6766592;       // 128*128
    float* bvec = ws + 6782976;       // 1024
    int*   flags= (int*)(ws + 6784000); // 2*1024 ints

    hipMemsetAsync(flags, 0, 2*N_TOK*sizeof(int), stream);

    k_gather<<<N_TOK, 128, 0, stream>>>(word_ids, pos_ids, wemb, pemb, x);
    k_transpose<<<dim3(8,8), dim3(16,16), 0, stream>>>(U1, Ut, FD);

    dim3 blk(256);
    // input projections (recurrence-free): Xf/Xb = x((rev)) @ Wih^T + bih + bhh
    k_gemm_nt<<<dim3(G4/64, N_TOK/64), blk, 0, stream>>>(x, Wih_f, bih_f, bhh_f, nullptr, Xf,
                                                         N_TOK, G4, DV, 0, 0);
    k_gemm_nt<<<dim3(G4/64, N_TOK/64), blk, 0, stream>>>(x, Wih_b, bih_b, bhh_b, nullptr, Xb,
                                                         N_TOK, G4, DV, 1, 0);
    // sequential recurrence
    k_lstm<<<2*GWG, 256, 0, stream>>>(Whh_f, Whh_b, Xf, Xb, h0, c0, hf, hb, flags);

    k_sr<<<N_TOK, 256, 0, stream>>>(hf, hb, sr);

    // MLPs
    k_gemm_nt<<<dim3(HID/64, N_TOK/64), blk, 0, stream>>>(sr, Wh1, bh1, nullptr, nullptr, T1h,
                                                          N_TOK, HID, 2*DV, 0, 1);
    k_gemm_nt<<<dim3(HID/64, N_TOK/64), blk, 0, stream>>>(sr, Wd1, bd1, nullptr, nullptr, T1d,
                                                          N_TOK, HID, 2*DV, 0, 1);
    k_gemm_nt<<<dim3(FD/64,  N_TOK/64), blk, 0, stream>>>(T1h, Wh2, bh2, nullptr, nullptr, Hh,
                                                          N_TOK, FD, HID, 0, 0);
    k_gemm_nt<<<dim3(FD/64,  N_TOK/64), blk, 0, stream>>>(T1d, Wd2, bd2, nullptr, nullptr, Hd,
                                                          N_TOK, FD, HID, 0, 0);
    // biaffine
    k_bvec<<<N_TOK, 64, 0, stream>>>(Hh, u2, bvec);
    k_gemm_nt<<<dim3(FD/64,  N_TOK/64), blk, 0, stream>>>(Hh, Ut, nullptr, nullptr, nullptr, G1,
                                                          N_TOK, FD, FD, 0, 0);
    k_gemm_nt<<<dim3(N_TOK/64, N_TOK/64), blk, 0, stream>>>(G1, Hd, nullptr, nullptr, bvec, out,
                                                            N_TOK, N_TOK, FD, 0, 0);
}

// Round 2
// 4489.923 us; speedup vs baseline: 3.1213x; 3.1213x over previous
//
#include <hip/hip_runtime.h>
#include <math.h>

#define N_TOK 1024
#define DV    400
#define G4    1600
#define DWD   300
#define DPD   100
#define HID   512
#define FD    128
#define GWG   50      // workgroups per LSTM direction
#define EPW   8       // hidden elements per WG (DV / GWG)

__device__ __forceinline__ float sigmoidf_(float x){ return 1.0f/(1.0f+__expf(-x)); }

// ---------------- embedding gather: x[t] = [word_emb[wid], pos_emb[pid]] ----------------
__global__ void k_gather(const int* __restrict__ wid, const int* __restrict__ pid,
                         const float* __restrict__ wemb, const float* __restrict__ pemb,
                         float* __restrict__ x)
{
    int t = blockIdx.x;
    int w = wid[t], p = pid[t];
    for (int k = threadIdx.x; k < DV; k += blockDim.x){
        float v = (k < DWD) ? wemb[(long)w*DWD + k] : pemb[p*DPD + (k - DWD)];
        x[t*DV + k] = v;
    }
}

// ---------------- tiny transpose (U_1 -> U_1^T) ----------------
__global__ void k_transpose(const float* __restrict__ U, float* __restrict__ Ut, int n)
{
    int j = blockIdx.y*16 + threadIdx.y;
    int k = blockIdx.x*16 + threadIdx.x;
    if (j < n && k < n) Ut[j*n + k] = U[k*n + j];
}

// ---------------- fp32 NT GEMM: C[M][Nn] = A[M][K] * B[Nn][K]^T (+biases, relu) -------
__global__ __launch_bounds__(256) void k_gemm_nt(
    const float* __restrict__ A, const float* __restrict__ B,
    const float* __restrict__ bias1, const float* __restrict__ bias2,
    const float* __restrict__ rowbias, float* __restrict__ C,
    int M, int Nn, int K, int revA, int relu)
{
    const int BM = 64, BN = 64, BK = 16;
    __shared__ float As[BK][BM];
    __shared__ float Bs[BK][BN];
    int tid = threadIdx.x;
    int tx = tid & 15, ty = tid >> 4;
    int m0 = blockIdx.y*BM, n0 = blockIdx.x*BN;
    int lrow = tid >> 2;          // 0..63
    int lk   = (tid & 3) * 4;     // 0,4,8,12
    float acc[4][4] = {{0.f}};

    for (int k0 = 0; k0 < K; k0 += BK){
        int am = m0 + lrow; if (revA) am = M - 1 - am;
        const float4 av = *(const float4*)&A[(long)am*K + k0 + lk];
        const float4 bv = *(const float4*)&B[(long)(n0 + lrow)*K + k0 + lk];
        As[lk+0][lrow] = av.x; As[lk+1][lrow] = av.y; As[lk+2][lrow] = av.z; As[lk+3][lrow] = av.w;
        Bs[lk+0][lrow] = bv.x; Bs[lk+1][lrow] = bv.y; Bs[lk+2][lrow] = bv.z; Bs[lk+3][lrow] = bv.w;
        __syncthreads();
        #pragma unroll
        for (int kk = 0; kk < BK; ++kk){
            const float4 a = *(const float4*)&As[kk][ty*4];
            const float4 b = *(const float4*)&Bs[kk][tx*4];
            const float ar[4] = {a.x, a.y, a.z, a.w};
            const float br[4] = {b.x, b.y, b.z, b.w};
            #pragma unroll
            for (int i = 0; i < 4; ++i)
                #pragma unroll
                for (int j = 0; j < 4; ++j)
                    acc[i][j] += ar[i]*br[j];
        }
        __syncthreads();
    }

    #pragma unroll
    for (int i = 0; i < 4; ++i){
        int m = m0 + ty*4 + i;
        float rb = rowbias ? rowbias[m] : 0.0f;
        #pragma unroll
        for (int j = 0; j < 4; ++j){
            int n = n0 + tx*4 + j;
            float v = acc[i][j] + rb;
            if (bias1) v += bias1[n];
            if (bias2) v += bias2[n];
            if (relu)  v = fmaxf(v, 0.0f);
            C[(long)m*Nn + n] = v;
        }
    }
}

// ---------------- persistent BiLSTM — relaxed-atomic step barrier (no cache maint) ------
// All cross-WG traffic (h values, flags) uses RELAXED agent-scope atomics only: these
// bypass L1/L2 to the IF$ coherence point, so no acquire-invalidate / release-writeback
// ever runs in the hot loop. Ordering h-store -> flag-store is enforced by an explicit
// s_waitcnt vmcnt(0) + __syncthreads (store already at coherence point when drained).
// Flags are per-(dir,step,WG) write-once cells -> no RMW contention, no ABA.
__global__ __launch_bounds__(256) void k_lstm(
    const float* __restrict__ Whh_f, const float* __restrict__ Whh_b,
    const float* __restrict__ Xf, const float* __restrict__ Xb,
    const float* __restrict__ h0, const float* __restrict__ c0,
    float* __restrict__ hf, float* __restrict__ hb,
    int* __restrict__ flags)
{
    __shared__ float W_s[32][DV];   // 51.2 KB
    __shared__ float h_s[DV];

    int tid = threadIdx.x;
    int dir = blockIdx.x / GWG;
    int g   = blockIdx.x % GWG;
    int j0  = g * EPW;
    const float* Whh = dir ? Whh_b : Whh_f;
    const float* XX  = dir ? Xb    : Xf;
    float*       hout= dir ? hb    : hf;

    // stage weight slice: local row r = q*8+e  ->  global gate row q*DV + j0 + e
    for (int idx = tid; idx < 32*DV; idx += 256){
        int r = idx / DV, k = idx % DV;
        int grow = (r >> 3) * DV + j0 + (r & 7);
        W_s[r][k] = Whh[(long)grow*DV + k];
    }
    for (int idx = tid; idx < DV; idx += 256) h_s[idx] = h0[dir*DV + idx];

    int w    = tid >> 6;        // wave 0..3
    int lane = tid & 63;
    int q    = lane >> 4;       // gate 0..3 (i,f,g,o)
    int eo   = (lane >> 3) & 1; // element parity within wave
    int l    = lane & 7;        // lane within row octet
    int e    = 2*w + eo;        // element 0..7 owned by this octet's wave
    int r    = q*8 + e;         // local weight row
    int grow = q*DV + j0 + e;   // global gate index
    bool owner = (q == 0) && (l == 0);  // lanes 0 and 8 of each wave
    float c_reg = owner ? c0[dir*DV + j0 + e] : 0.0f;
    __syncthreads();

    bool dead = false;
    for (int t = 0; t < N_TOK; ++t){
        float xv = 0.0f;
        if (l == 0) xv = XX[(long)t*G4 + grow];   // issued early, consumed after dot

        // matvec: row r dot h  (8 lanes/row, float2 each)
        float sum = 0.0f;
        const float2* wrow = (const float2*)&W_s[r][0];
        const float2* hp   = (const float2*)&h_s[0];
        #pragma unroll
        for (int i = 0; i < 25; ++i){
            float2 wv = wrow[l + 8*i];
            float2 hv = hp[l + 8*i];
            sum += wv.x*hv.x + wv.y*hv.y;
        }
        sum += __shfl_xor(sum, 1, 8);
        sum += __shfl_xor(sum, 2, 8);
        sum += __shfl_xor(sum, 4, 8);
        if (l == 0) sum += xv;

        // collect the 4 gate totals for my wave's element e (srcs are l==0 lanes)
        float gi = __shfl(sum, eo*8 + 0,  64);
        float gf = __shfl(sum, eo*8 + 16, 64);
        float gg = __shfl(sum, eo*8 + 32, 64);
        float go = __shfl(sum, eo*8 + 48, 64);

        if (owner){
            float iv = sigmoidf_(gi);
            float fv = sigmoidf_(gf);
            float gv = tanhf(gg);
            float ov = sigmoidf_(go);
            c_reg = fv*c_reg + iv*gv;
            float hv = ov * tanhf(c_reg);
            __hip_atomic_store(&hout[(long)t*DV + j0 + e], hv,
                               __ATOMIC_RELAXED, __HIP_MEMORY_SCOPE_AGENT);
        }
        // drain h stores to the coherence point, then publish our flag
        asm volatile("s_waitcnt vmcnt(0)" ::: "memory");
        __syncthreads();
        int* frow = flags + ((dir*N_TOK + t) << 6);
        if (tid == 0)
            __hip_atomic_store(&frow[g], 1, __ATOMIC_RELAXED, __HIP_MEMORY_SCOPE_AGENT);

        // poll all GWG flags with one 50-lane relaxed load + ballot (no invalidates)
        if (!dead){
            int guard = 0;
            for (;;){
                int v = (lane < GWG)
                    ? __hip_atomic_load(&frow[lane], __ATOMIC_RELAXED, __HIP_MEMORY_SCOPE_AGENT)
                    : 1;
                if (__all(v != 0)) break;
                if (++guard > (1 << 18)) { dead = true; break; }  // safety: no infinite hang
            }
        }
        // restage full h[t] (relaxed agent loads: read IF$ directly, always fresh)
        for (int idx = tid; idx < DV; idx += 256)
            h_s[idx] = __hip_atomic_load(&hout[(long)t*DV + idx],
                                         __ATOMIC_RELAXED, __HIP_MEMORY_SCOPE_AGENT);
        __syncthreads();
    }
}

// ---------------- sr = sigmoid(concat(hf[t], hb[N-1-t])) ----------------
__global__ void k_sr(const float* __restrict__ hf, const float* __restrict__ hb,
                     float* __restrict__ sr)
{
    int t = blockIdx.x;
    for (int c = threadIdx.x; c < 2*DV; c += blockDim.x){
        float v = (c < DV) ? hf[t*DV + c] : hb[(N_TOK-1-t)*DV + (c - DV)];
        sr[t*2*DV + c] = 1.0f/(1.0f+__expf(-v));
    }
}

// ---------------- bvec[i] = dot(Hh[i], u2) ----------------
__global__ void k_bvec(const float* __restrict__ Hh, const float* __restrict__ u2,
                       float* __restrict__ bvec)
{
    int i = blockIdx.x;
    int lane = threadIdx.x;
    float v = Hh[i*FD + lane]*u2[lane] + Hh[i*FD + 64 + lane]*u2[64 + lane];
    v += __shfl_xor(v, 1, 64);
    v += __shfl_xor(v, 2, 64);
    v += __shfl_xor(v, 4, 64);
    v += __shfl_xor(v, 8, 64);
    v += __shfl_xor(v, 16, 64);
    v += __shfl_xor(v, 32, 64);
    if (lane == 0) bvec[i] = v;
}

extern "C" void kernel_launch(void* const* d_in, const int* in_sizes, int n_in,
                              void* d_out, int out_size, void* d_ws, size_t ws_size,
                              hipStream_t stream)
{
    const int*   word_ids = (const int*)  d_in[0];
    const int*   pos_ids  = (const int*)  d_in[1];
    const float* h0    = (const float*)d_in[2];
    const float* c0    = (const float*)d_in[3];
    const float* wemb  = (const float*)d_in[4];
    const float* pemb  = (const float*)d_in[5];
    const float* Wih_f = (const float*)d_in[6];
    const float* Whh_f = (const float*)d_in[7];
    const float* bih_f = (const float*)d_in[8];
    const float* bhh_f = (const float*)d_in[9];
    const float* Wih_b = (const float*)d_in[10];
    const float* Whh_b = (const float*)d_in[11];
    const float* bih_b = (const float*)d_in[12];
    const float* bhh_b = (const float*)d_in[13];
    const float* Wh1   = (const float*)d_in[14];
    const float* bh1   = (const float*)d_in[15];
    const float* Wh2   = (const float*)d_in[16];
    const float* bh2   = (const float*)d_in[17];
    const float* Wd1   = (const float*)d_in[18];
    const float* bd1   = (const float*)d_in[19];
    const float* Wd2   = (const float*)d_in[20];
    const float* bd2   = (const float*)d_in[21];
    const float* U1    = (const float*)d_in[22];
    const float* u2    = (const float*)d_in[23];
    float* out = (float*)d_out;

    // workspace layout (floats)
    float* ws  = (float*)d_ws;
    float* x    = ws;                 // 1024*400
    float* Xf   = ws + 409600;        // 1024*1600
    float* Xb   = ws + 2048000;       // 1024*1600
    float* hf   = ws + 3686400;       // 1024*400
    float* hb   = ws + 4096000;       // 1024*400
    float* sr   = ws + 4505600;       // 1024*800
    float* T1h  = ws + 5324800;       // 1024*512
    float* T1d  = ws + 5849088;       // 1024*512
    float* Hh   = ws + 6373376;       // 1024*128
    float* Hd   = ws + 6504448;       // 1024*128
    float* G1   = ws + 6635520;       // 1024*128
    float* Ut   = ws + 6766592;       // 128*128
    float* bvec = ws + 6782976;       // 1024
    int*   flags= (int*)(ws + 6784000); // 2*1024*64 ints (per-dir, per-step, per-WG cells)

    hipMemsetAsync(flags, 0, 2*N_TOK*64*sizeof(int), stream);

    k_gather<<<N_TOK, 128, 0, stream>>>(word_ids, pos_ids, wemb, pemb, x);
    k_transpose<<<dim3(8,8), dim3(16,16), 0, stream>>>(U1, Ut, FD);

    dim3 blk(256);
    // input projections (recurrence-free): Xf/Xb = x((rev)) @ Wih^T + bih + bhh
    k_gemm_nt<<<dim3(G4/64, N_TOK/64), blk, 0, stream>>>(x, Wih_f, bih_f, bhh_f, nullptr, Xf,
                                                         N_TOK, G4, DV, 0, 0);
    k_gemm_nt<<<dim3(G4/64, N_TOK/64), blk, 0, stream>>>(x, Wih_b, bih_b, bhh_b, nullptr, Xb,
                                                         N_TOK, G4, DV, 1, 0);
    // sequential recurrence
    k_lstm<<<2*GWG, 256, 0, stream>>>(Whh_f, Whh_b, Xf, Xb, h0, c0, hf, hb, flags);

    k_sr<<<N_TOK, 256, 0, stream>>>(hf, hb, sr);

    // MLPs
    k_gemm_nt<<<dim3(HID/64, N_TOK/64), blk, 0, stream>>>(sr, Wh1, bh1, nullptr, nullptr, T1h,
                                                          N_TOK, HID, 2*DV, 0, 1);
    k_gemm_nt<<<dim3(HID/64, N_TOK/64), blk, 0, stream>>>(sr, Wd1, bd1, nullptr, nullptr, T1d,
                                                          N_TOK, HID, 2*DV, 0, 1);
    k_gemm_nt<<<dim3(FD/64,  N_TOK/64), blk, 0, stream>>>(T1h, Wh2, bh2, nullptr, nullptr, Hh,
                                                          N_TOK, FD, HID, 0, 0);
    k_gemm_nt<<<dim3(FD/64,  N_TOK/64), blk, 0, stream>>>(T1d, Wd2, bd2, nullptr, nullptr, Hd,
                                                          N_TOK, FD, HID, 0, 0);
    // biaffine
    k_bvec<<<N_TOK, 64, 0, stream>>>(Hh, u2, bvec);
    k_gemm_nt<<<dim3(FD/64,  N_TOK/64), blk, 0, stream>>>(Hh, Ut, nullptr, nullptr, nullptr, G1,
                                                          N_TOK, FD, FD, 0, 0);
    k_gemm_nt<<<dim3(N_TOK/64, N_TOK/64), blk, 0, stream>>>(G1, Hd, nullptr, nullptr, bvec, out,
                                                            N_TOK, N_TOK, FD, 0, 0);
}

// Round 3
// 2654.862 us; speedup vs baseline: 5.2788x; 1.6912x over previous
//
#include <hip/hip_runtime.h>
#include <math.h>

#define N_TOK 1024
#define DV    400
#define G4    1600
#define DWD   300
#define DPD   100
#define HID   512
#define FD    128
#define GWG   50      // workgroups per LSTM direction
#define EPW   8       // hidden elements per WG (DV / GWG)

__device__ __forceinline__ float sigmoidf_(float x){ return 1.0f/(1.0f+__expf(-x)); }

// ---------------- embedding gather: x[t] = [word_emb[wid], pos_emb[pid]] ----------------
__global__ void k_gather(const int* __restrict__ wid, const int* __restrict__ pid,
                         const float* __restrict__ wemb, const float* __restrict__ pemb,
                         float* __restrict__ x)
{
    int t = blockIdx.x;
    int w = wid[t], p = pid[t];
    for (int k = threadIdx.x; k < DV; k += blockDim.x){
        float v = (k < DWD) ? wemb[(long)w*DWD + k] : pemb[p*DPD + (k - DWD)];
        x[t*DV + k] = v;
    }
}

// ---------------- tiny transpose (U_1 -> U_1^T) ----------------
__global__ void k_transpose(const float* __restrict__ U, float* __restrict__ Ut, int n)
{
    int j = blockIdx.y*16 + threadIdx.y;
    int k = blockIdx.x*16 + threadIdx.x;
    if (j < n && k < n) Ut[j*n + k] = U[k*n + j];
}

// ---------------- fp32 NT GEMM: C[M][Nn] = A[M][K] * B[Nn][K]^T (+biases, relu) -------
__global__ __launch_bounds__(256) void k_gemm_nt(
    const float* __restrict__ A, const float* __restrict__ B,
    const float* __restrict__ bias1, const float* __restrict__ bias2,
    const float* __restrict__ rowbias, float* __restrict__ C,
    int M, int Nn, int K, int revA, int relu)
{
    const int BM = 64, BN = 64, BK = 16;
    __shared__ float As[BK][BM];
    __shared__ float Bs[BK][BN];
    int tid = threadIdx.x;
    int tx = tid & 15, ty = tid >> 4;
    int m0 = blockIdx.y*BM, n0 = blockIdx.x*BN;
    int lrow = tid >> 2;          // 0..63
    int lk   = (tid & 3) * 4;     // 0,4,8,12
    float acc[4][4] = {{0.f}};

    for (int k0 = 0; k0 < K; k0 += BK){
        int am = m0 + lrow; if (revA) am = M - 1 - am;
        const float4 av = *(const float4*)&A[(long)am*K + k0 + lk];
        const float4 bv = *(const float4*)&B[(long)(n0 + lrow)*K + k0 + lk];
        As[lk+0][lrow] = av.x; As[lk+1][lrow] = av.y; As[lk+2][lrow] = av.z; As[lk+3][lrow] = av.w;
        Bs[lk+0][lrow] = bv.x; Bs[lk+1][lrow] = bv.y; Bs[lk+2][lrow] = bv.z; Bs[lk+3][lrow] = bv.w;
        __syncthreads();
        #pragma unroll
        for (int kk = 0; kk < BK; ++kk){
            const float4 a = *(const float4*)&As[kk][ty*4];
            const float4 b = *(const float4*)&Bs[kk][tx*4];
            const float ar[4] = {a.x, a.y, a.z, a.w};
            const float br[4] = {b.x, b.y, b.z, b.w};
            #pragma unroll
            for (int i = 0; i < 4; ++i)
                #pragma unroll
                for (int j = 0; j < 4; ++j)
                    acc[i][j] += ar[i]*br[j];
        }
        __syncthreads();
    }

    #pragma unroll
    for (int i = 0; i < 4; ++i){
        int m = m0 + ty*4 + i;
        float rb = rowbias ? rowbias[m] : 0.0f;
        #pragma unroll
        for (int j = 0; j < 4; ++j){
            int n = n0 + tx*4 + j;
            float v = acc[i][j] + rb;
            if (bias1) v += bias1[n];
            if (bias2) v += bias2[n];
            if (relu)  v = fmaxf(v, 0.0f);
            C[(long)m*Nn + n] = v;
        }
    }
}

// ---------------- persistent BiLSTM — single-round-trip mailbox handshake --------------
// Producers publish each h element as ONE 64-bit relaxed agent-scope atomic store of
// (tag<<32)|bits(h) into a per-(dir,t,element) mailbox slot (zeroed each call). An 8-byte
// atomic is indivisible, so tag!=0 => value valid: consumers poll the DATA directly.
// No flags, no vmcnt drains, no separate restage pass => critical path per step is
// compute + one store->visible latency. Own-WG elements bypass the mailbox via LDS.
__global__ __launch_bounds__(256) void k_lstm(
    const float* __restrict__ Whh_f, const float* __restrict__ Whh_b,
    const float* __restrict__ Xf, const float* __restrict__ Xb,
    const float* __restrict__ h0, const float* __restrict__ c0,
    float* __restrict__ hf, float* __restrict__ hb,
    unsigned long long* __restrict__ mbox)
{
    __shared__ float W_s[32][DV];   // 51.2 KB
    __shared__ float h_s[DV];

    int tid = threadIdx.x;
    int dir = blockIdx.x / GWG;
    int g   = blockIdx.x % GWG;
    int j0  = g * EPW;
    const float* Whh = dir ? Whh_b : Whh_f;
    const float* XX  = dir ? Xb    : Xf;
    float*       hout= dir ? hb    : hf;
    unsigned long long* mb = mbox + (size_t)dir * N_TOK * DV;

    // stage weight slice: local row r = q*8+e  ->  global gate row q*DV + j0 + e
    for (int idx = tid; idx < 32*DV; idx += 256){
        int r = idx / DV, k = idx % DV;
        int grow = (r >> 3) * DV + j0 + (r & 7);
        W_s[r][k] = Whh[(long)grow*DV + k];
    }
    for (int idx = tid; idx < DV; idx += 256) h_s[idx] = h0[dir*DV + idx];

    int w    = tid >> 6;        // wave 0..3
    int lane = tid & 63;
    int q    = lane >> 4;       // gate 0..3 (i,f,g,o)
    int eo   = (lane >> 3) & 1; // element parity within wave
    int l    = lane & 7;        // lane within row octet
    int e    = 2*w + eo;        // element 0..7 owned by this octet's wave
    int r    = q*8 + e;         // local weight row
    int grow = q*DV + j0 + e;   // global gate index
    bool owner = (q == 0) && (l == 0);  // lanes 0 and 8 of each wave
    float c_reg = owner ? c0[dir*DV + j0 + e] : 0.0f;

    // consumer slot assignment: thread tid polls slot tid (and 256+tid if tid<144)
    int s0 = tid;
    int s1 = 256 + tid;
    bool own0 = (s0 >= j0) && (s0 < j0 + EPW);
    bool own1 = (tid < 144) && (s1 >= j0) && (s1 < j0 + EPW);
    __syncthreads();

    // prefetch X for t=0
    float xv_n = 0.0f;
    if (l == 0) xv_n = XX[grow];

    bool dead = false;
    for (int t = 0; t < N_TOK; ++t){
        float xv = xv_n;

        // matvec: row r dot h  (8 lanes/row, float2 each)
        float sum = 0.0f;
        const float2* wrow = (const float2*)&W_s[r][0];
        const float2* hp   = (const float2*)&h_s[0];
        #pragma unroll
        for (int i = 0; i < 25; ++i){
            float2 wv = wrow[l + 8*i];
            float2 hv = hp[l + 8*i];
            sum += wv.x*hv.x + wv.y*hv.y;
        }
        sum += __shfl_xor(sum, 1, 8);
        sum += __shfl_xor(sum, 2, 8);
        sum += __shfl_xor(sum, 4, 8);
        if (l == 0) sum += xv;

        // collect the 4 gate totals for my wave's element e (srcs are l==0 lanes)
        float gi = __shfl(sum, eo*8 + 0,  64);
        float gf = __shfl(sum, eo*8 + 16, 64);
        float gg = __shfl(sum, eo*8 + 32, 64);
        float go = __shfl(sum, eo*8 + 48, 64);

        float h_new = 0.0f;
        if (owner){
            float iv = sigmoidf_(gi);
            float fv = sigmoidf_(gf);
            float gv = tanhf(gg);
            float ov = sigmoidf_(go);
            c_reg = fv*c_reg + iv*gv;
            h_new = ov * tanhf(c_reg);
            // publish: one indivisible 8B store (tag|value) straight to coherence point
            unsigned long long pk = (1ull << 32) | (unsigned long long)__float_as_uint(h_new);
            __hip_atomic_store(&mb[(size_t)t*DV + j0 + e], pk,
                               __ATOMIC_RELAXED, __HIP_MEMORY_SCOPE_AGENT);
            hout[(long)t*DV + j0 + e] = h_new;   // plain store for post-LSTM consumers
        }

        __syncthreads();   // all waves done READING h_s for this step

        // own elements bypass the mailbox
        if (owner) h_s[j0 + e] = h_new;

        // prefetch next step's X while we wait (hides HBM latency under the poll)
        if (l == 0){
            int tn = (t + 1 < N_TOK) ? (t + 1) : t;
            xv_n = XX[(size_t)tn*G4 + grow];
        }

        // poll remote slots; 8B atomicity makes tag!=0 imply value valid
        const unsigned long long* mrow = &mb[(size_t)t*DV];
        float v0 = 0.0f, v1 = 0.0f;
        bool g0 = own0, g1 = own1 || (tid >= 144);
        if (!dead){
            int guard = 0;
            while (!(g0 && g1)){
                if (!g0){
                    unsigned long long u = __hip_atomic_load(&mrow[s0],
                                         __ATOMIC_RELAXED, __HIP_MEMORY_SCOPE_AGENT);
                    if (u >> 32){ v0 = __uint_as_float((unsigned)u); g0 = true; }
                }
                if (!g1){
                    unsigned long long u = __hip_atomic_load(&mrow[s1],
                                         __ATOMIC_RELAXED, __HIP_MEMORY_SCOPE_AGENT);
                    if (u >> 32){ v1 = __uint_as_float((unsigned)u); g1 = true; }
                }
                if (++guard > (1 << 16)) { dead = true; break; }  // no-hang safety
            }
            if (!own0 && g0) h_s[s0] = v0;
            if (tid < 144 && !own1 && g1) h_s[s1] = v1;
        }
        __syncthreads();
    }
}

// ---------------- sr = sigmoid(concat(hf[t], hb[N-1-t])) ----------------
__global__ void k_sr(const float* __restrict__ hf, const float* __restrict__ hb,
                     float* __restrict__ sr)
{
    int t = blockIdx.x;
    for (int c = threadIdx.x; c < 2*DV; c += blockDim.x){
        float v = (c < DV) ? hf[t*DV + c] : hb[(N_TOK-1-t)*DV + (c - DV)];
        sr[t*2*DV + c] = 1.0f/(1.0f+__expf(-v));
    }
}

// ---------------- bvec[i] = dot(Hh[i], u2) ----------------
__global__ void k_bvec(const float* __restrict__ Hh, const float* __restrict__ u2,
                       float* __restrict__ bvec)
{
    int i = blockIdx.x;
    int lane = threadIdx.x;
    float v = Hh[i*FD + lane]*u2[lane] + Hh[i*FD + 64 + lane]*u2[64 + lane];
    v += __shfl_xor(v, 1, 64);
    v += __shfl_xor(v, 2, 64);
    v += __shfl_xor(v, 4, 64);
    v += __shfl_xor(v, 8, 64);
    v += __shfl_xor(v, 16, 64);
    v += __shfl_xor(v, 32, 64);
    if (lane == 0) bvec[i] = v;
}

extern "C" void kernel_launch(void* const* d_in, const int* in_sizes, int n_in,
                              void* d_out, int out_size, void* d_ws, size_t ws_size,
                              hipStream_t stream)
{
    const int*   word_ids = (const int*)  d_in[0];
    const int*   pos_ids  = (const int*)  d_in[1];
    const float* h0    = (const float*)d_in[2];
    const float* c0    = (const float*)d_in[3];
    const float* wemb  = (const float*)d_in[4];
    const float* pemb  = (const float*)d_in[5];
    const float* Wih_f = (const float*)d_in[6];
    const float* Whh_f = (const float*)d_in[7];
    const float* bih_f = (const float*)d_in[8];
    const float* bhh_f = (const float*)d_in[9];
    const float* Wih_b = (const float*)d_in[10];
    const float* Whh_b = (const float*)d_in[11];
    const float* bih_b = (const float*)d_in[12];
    const float* bhh_b = (const float*)d_in[13];
    const float* Wh1   = (const float*)d_in[14];
    const float* bh1   = (const float*)d_in[15];
    const float* Wh2   = (const float*)d_in[16];
    const float* bh2   = (const float*)d_in[17];
    const float* Wd1   = (const float*)d_in[18];
    const float* bd1   = (const float*)d_in[19];
    const float* Wd2   = (const float*)d_in[20];
    const float* bd2   = (const float*)d_in[21];
    const float* U1    = (const float*)d_in[22];
    const float* u2    = (const float*)d_in[23];
    float* out = (float*)d_out;

    // workspace layout (floats)
    float* ws  = (float*)d_ws;
    float* x    = ws;                 // 1024*400
    float* Xf   = ws + 409600;        // 1024*1600
    float* Xb   = ws + 2048000;       // 1024*1600
    float* hf   = ws + 3686400;       // 1024*400
    float* hb   = ws + 4096000;       // 1024*400
    float* sr   = ws + 4505600;       // 1024*800   (aliased by mbox during LSTM)
    float* T1h  = ws + 5324800;       // 1024*512   (aliased by mbox during LSTM)
    float* T1d  = ws + 5849088;       // 1024*512   (partially aliased by mbox)
    float* Hh   = ws + 6373376;       // 1024*128
    float* Hd   = ws + 6504448;       // 1024*128
    float* G1   = ws + 6635520;       // 1024*128
    float* Ut   = ws + 6766592;       // 128*128
    float* bvec = ws + 6782976;       // 1024
    // mailbox: 2*1024*400 slots x 8B = 6.55 MB, lives in [4505600, 6144000) floats.
    // Only used during k_lstm; sr/T1h/T1d are written strictly after k_lstm completes.
    unsigned long long* mbox = (unsigned long long*)(ws + 4505600);

    hipMemsetAsync(mbox, 0, (size_t)2*N_TOK*DV*sizeof(unsigned long long), stream);

    k_gather<<<N_TOK, 128, 0, stream>>>(word_ids, pos_ids, wemb, pemb, x);
    k_transpose<<<dim3(8,8), dim3(16,16), 0, stream>>>(U1, Ut, FD);

    dim3 blk(256);
    // input projections (recurrence-free): Xf/Xb = x((rev)) @ Wih^T + bih + bhh
    k_gemm_nt<<<dim3(G4/64, N_TOK/64), blk, 0, stream>>>(x, Wih_f, bih_f, bhh_f, nullptr, Xf,
                                                         N_TOK, G4, DV, 0, 0);
    k_gemm_nt<<<dim3(G4/64, N_TOK/64), blk, 0, stream>>>(x, Wih_b, bih_b, bhh_b, nullptr, Xb,
                                                         N_TOK, G4, DV, 1, 0);
    // sequential recurrence
    k_lstm<<<2*GWG, 256, 0, stream>>>(Whh_f, Whh_b, Xf, Xb, h0, c0, hf, hb, mbox);

    k_sr<<<N_TOK, 256, 0, stream>>>(hf, hb, sr);

    // MLPs
    k_gemm_nt<<<dim3(HID/64, N_TOK/64), blk, 0, stream>>>(sr, Wh1, bh1, nullptr, nullptr, T1h,
                                                          N_TOK, HID, 2*DV, 0, 1);
    k_gemm_nt<<<dim3(HID/64, N_TOK/64), blk, 0, stream>>>(sr, Wd1, bd1, nullptr, nullptr, T1d,
                                                          N_TOK, HID, 2*DV, 0, 1);
    k_gemm_nt<<<dim3(FD/64,  N_TOK/64), blk, 0, stream>>>(T1h, Wh2, bh2, nullptr, nullptr, Hh,
                                                          N_TOK, FD, HID, 0, 0);
    k_gemm_nt<<<dim3(FD/64,  N_TOK/64), blk, 0, stream>>>(T1d, Wd2, bd2, nullptr, nullptr, Hd,
                                                          N_TOK, FD, HID, 0, 0);
    // biaffine
    k_bvec<<<N_TOK, 64, 0, stream>>>(Hh, u2, bvec);
    k_gemm_nt<<<dim3(FD/64,  N_TOK/64), blk, 0, stream>>>(Hh, Ut, nullptr, nullptr, nullptr, G1,
                                                          N_TOK, FD, FD, 0, 0);
    k_gemm_nt<<<dim3(N_TOK/64, N_TOK/64), blk, 0, stream>>>(G1, Hd, nullptr, nullptr, bvec, out,
                                                            N_TOK, N_TOK, FD, 0, 0);
}